// Round 4
// baseline (73.436 us; speedup 1.0000x reference)
//
#include <hip/hip_runtime.h>

#define LAMB_COORD 5.0f
#define LAMB_NOOBJ 0.5f
#define GEPS 1e-7f

// gt/pred: (B=16384, C=30, H=7, W=7) fp32. Record = 1470 floats (30 ch x 49 cells).
// Block = 256 threads owns NB=4 consecutive records.
//   Phase 1: stage front (ch 0..9, first 490 floats of each record, CONTIGUOUS)
//            of gt and pred into LDS via coalesced float2 loads.
//   Phase 2: 196 threads compute the per-cell front loss (GIoU pick, xy/wh/conf)
//            from LDS and write appears[cell] to LDS.
//   Phase 3: stream the class region (ch 10..29, 980 contiguous floats/record)
//            with float2 loads + LDS appears gather (stride-2 -> 2-way, free).
// Records are 8B-aligned (1470*4 = 5880 B), so float2 is always legal.

#define NB      4
#define RECF    1470
#define FRONTF  490
#define CLSF    980
#define FRONT2  (FRONTF / 2)    // 245 float2 per record
#define CLS2    (CLSF / 2)      // 490 float2 per record
#define NFRONT2 (NB * FRONT2)   // 980
#define NCLS2   (NB * CLS2)     // 1960

__global__ __launch_bounds__(256) void yolo_loss_kernel(
        const float* __restrict__ gt, const float* __restrict__ pred,
        float* __restrict__ out) {
    __shared__ float2 gF2[NB * FRONT2];   // 7840 B
    __shared__ float2 pF2[NB * FRONT2];   // 7840 B
    __shared__ float  app[NB * 49];       // 784 B

    const int tid = threadIdx.x;
    const size_t base = (size_t)blockIdx.x * (NB * RECF);
    const float* __restrict__ g0 = gt + base;
    const float* __restrict__ p0 = pred + base;

    // ---- Phase 1: stage front segments (all loads issued before LDS writes) ----
    float2 sg[4], sp[4];
    int sidx[4];
    #pragma unroll
    for (int k = 0; k < 4; ++k) {
        int idx = tid + k * 256;
        bool ok = idx < NFRONT2;
        int ii = ok ? idx : 0;
        int rr = ii / FRONT2;
        int q  = ii - rr * FRONT2;
        sg[k] = *((const float2*)(g0 + rr * RECF) + q);
        sp[k] = *((const float2*)(p0 + rr * RECF) + q);
        sidx[k] = ok ? (rr * FRONT2 + q) : -1;
    }
    #pragma unroll
    for (int k = 0; k < 4; ++k) {
        if (sidx[k] >= 0) { gF2[sidx[k]] = sg[k]; pF2[sidx[k]] = sp[k]; }
    }
    __syncthreads();

    // ---- Phase 2: per-cell front loss ----
    const float* gF = (const float*)gF2;
    const float* pF = (const float*)pF2;
    float s = 0.0f;
    if (tid < NB * 49) {
        const int rr = tid / 49;
        const int hw = tid - rr * 49;
        const float* __restrict__ g = gF + rr * FRONTF + hw;
        const float* __restrict__ p = pF + rr * FRONTF + hw;

        float gv[10], pv[10];
        #pragma unroll
        for (int c = 0; c < 10; ++c) { gv[c] = g[c * 49]; pv[c] = p[c * 49]; }

        const float gx1 = gv[0], gy1 = gv[1];
        const float gx2 = gv[0] + gv[2], gy2 = gv[1] + gv[3];
        const float ga  = (gx2 - gx1) * (gy2 - gy1);

        float l[2];
        #pragma unroll
        for (int k = 0; k < 2; ++k) {
            const int o = k * 5;
            float px1 = pv[o + 0], py1 = pv[o + 1];
            float px2 = px1 + pv[o + 2], py2 = py1 + pv[o + 3];
            float ix1 = fmaxf(gx1, px1), iy1 = fmaxf(gy1, py1);
            float ix2 = fminf(gx2, px2), iy2 = fminf(gy2, py2);
            float inter = fmaxf(ix2 - ix1, 0.0f) * fmaxf(iy2 - iy1, 0.0f);
            float pa  = (px2 - px1) * (py2 - py1);
            float uni = ga + pa - inter;
            float iou = inter / (uni + GEPS);
            float cx1 = fminf(gx1, px1), cy1 = fminf(gy1, py1);
            float cx2 = fmaxf(gx2, px2), cy2 = fmaxf(gy2, py2);
            float enc = (cx2 - cx1) * (cy2 - cy1);
            l[k] = 1.0f - (iou - (enc - uni) / (enc + GEPS));
        }

        // jnp.argmax first-max tie-break: arg = 1 iff l2 > l1
        float r0, r1;
        if (l[1] > l[0]) { r0 = 0.0f;   r1 = gv[9]; }
        else             { r0 = gv[4];  r1 = 0.0f;  }
        const float appears = fmaxf(r0, r1);
        app[tid] = appears;

        float d;
        d = gv[0] - pv[0]; s += d * d * r0 * LAMB_COORD;
        d = gv[1] - pv[1]; s += d * d * r0 * LAMB_COORD;
        d = gv[5] - pv[5]; s += d * d * r1 * LAMB_COORD;
        d = gv[6] - pv[6]; s += d * d * r1 * LAMB_COORD;
        d = sqrtf(gv[2]) - sqrtf(pv[2]); s += d * d * r0 * LAMB_COORD;
        d = sqrtf(gv[3]) - sqrtf(pv[3]); s += d * d * r0 * LAMB_COORD;
        d = sqrtf(gv[7]) - sqrtf(pv[7]); s += d * d * r1 * LAMB_COORD;
        d = sqrtf(gv[8]) - sqrtf(pv[8]); s += d * d * r1 * LAMB_COORD;
        d = gv[4] - pv[4]; { float d2 = d * d; s += d2 * r0 + d2 * (1.0f - r0) * LAMB_NOOBJ; }
        d = gv[9] - pv[9]; { float d2 = d * d; s += d2 * r1 + d2 * (1.0f - r1) * LAMB_NOOBJ; }
    }
    __syncthreads();

    // ---- Phase 3: stream class region with appears gather ----
    #pragma unroll
    for (int k = 0; k < 8; ++k) {
        int idx = tid + k * 256;
        if (idx < NCLS2) {
            int rr = idx / CLS2;
            int q  = idx - rr * CLS2;
            float2 gv = *((const float2*)(g0 + rr * RECF + FRONTF) + q);
            float2 pv = *((const float2*)(p0 + rr * RECF + FRONTF) + q);
            int r  = FRONTF + 2 * q;          // element index within record
            int c  = r / 49;
            int hw = r - c * 49;
            int hw1 = (hw == 48) ? 0 : hw + 1;
            float a0 = app[rr * 49 + hw];
            float a1 = app[rr * 49 + hw1];
            float d0 = gv.x - pv.x;
            float d1 = gv.y - pv.y;
            s += d0 * d0 * a0 + d1 * d1 * a1;
        }
    }

    // ---- Reduce: wave shuffle -> LDS -> one atomic per block ----
    #pragma unroll
    for (int off = 32; off > 0; off >>= 1)
        s += __shfl_down(s, off, 64);

    __shared__ float wsum[4];
    const int lane = tid & 63;
    const int wid  = tid >> 6;
    if (lane == 0) wsum[wid] = s;
    __syncthreads();
    if (tid == 0) {
        atomicAdd(out, wsum[0] + wsum[1] + wsum[2] + wsum[3]);
    }
}

extern "C" void kernel_launch(void* const* d_in, const int* in_sizes, int n_in,
                              void* d_out, int out_size, void* d_ws, size_t ws_size,
                              hipStream_t stream) {
    const float* gt   = (const float*)d_in[0];
    const float* pred = (const float*)d_in[1];
    float* out = (float*)d_out;

    const int B = in_sizes[0] / RECF;    // 16384
    const int grid = B / NB;             // 4096

    hipMemsetAsync(out, 0, sizeof(float) * out_size, stream);
    yolo_loss_kernel<<<grid, 256, 0, stream>>>(gt, pred, out);
}

// Round 5
// 62.087 us; speedup vs baseline: 1.1828x; 1.1828x over previous
//
#include <hip/hip_runtime.h>

#define LAMB_COORD 5.0f
#define LAMB_NOOBJ 0.5f
#define GEPS 1e-7f

// gt/pred: (B=16384, C=30, H=7, W=7) fp32. One thread per cell (b,hw).
// All 60 stride-49 channel loads are issued as back-to-back inline-asm
// global_load_dword (forced MLP: compiler must keep all 60 dests live),
// then a single s_waitcnt vmcnt(0) + sched_barrier(0) before consumption.
// ncells = 16384*49 = 802816 = 3136 * 256 exactly -> no tail predicate.

// offset imm is 13-bit signed (max 4095): channels 0..20 from base,
// channels 21..29 from base + 21*49 floats.
#define GLD(dst, base, OFF) \
    asm volatile("global_load_dword %0, %1, off offset:" OFF \
                 : "=v"(dst) : "v"(base))

__global__ __launch_bounds__(256) void yolo_loss_kernel(
        const float* __restrict__ gt, const float* __restrict__ pred,
        float* __restrict__ out) {
    const int i  = blockIdx.x * 256 + threadIdx.x;
    const int b  = i / 49;
    const int hw = i - b * 49;
    const float* g  = gt   + (size_t)b * 1470 + hw;
    const float* p  = pred + (size_t)b * 1470 + hw;
    const float* g2 = g + 21 * 49;
    const float* p2 = p + 21 * 49;

    float gv[30], pv[30];

    // ---- Issue ALL 60 loads before any wait/use (forced in-flight) ----
    GLD(gv[0],  g,  "0");    GLD(gv[1],  g,  "196");  GLD(gv[2],  g,  "392");
    GLD(gv[3],  g,  "588");  GLD(gv[4],  g,  "784");  GLD(gv[5],  g,  "980");
    GLD(gv[6],  g,  "1176"); GLD(gv[7],  g,  "1372"); GLD(gv[8],  g,  "1568");
    GLD(gv[9],  g,  "1764"); GLD(gv[10], g,  "1960"); GLD(gv[11], g,  "2156");
    GLD(gv[12], g,  "2352"); GLD(gv[13], g,  "2548"); GLD(gv[14], g,  "2744");
    GLD(gv[15], g,  "2940"); GLD(gv[16], g,  "3136"); GLD(gv[17], g,  "3332");
    GLD(gv[18], g,  "3528"); GLD(gv[19], g,  "3724"); GLD(gv[20], g,  "3920");
    GLD(gv[21], g2, "0");    GLD(gv[22], g2, "196");  GLD(gv[23], g2, "392");
    GLD(gv[24], g2, "588");  GLD(gv[25], g2, "784");  GLD(gv[26], g2, "980");
    GLD(gv[27], g2, "1176"); GLD(gv[28], g2, "1372"); GLD(gv[29], g2, "1568");

    GLD(pv[0],  p,  "0");    GLD(pv[1],  p,  "196");  GLD(pv[2],  p,  "392");
    GLD(pv[3],  p,  "588");  GLD(pv[4],  p,  "784");  GLD(pv[5],  p,  "980");
    GLD(pv[6],  p,  "1176"); GLD(pv[7],  p,  "1372"); GLD(pv[8],  p,  "1568");
    GLD(pv[9],  p,  "1764"); GLD(pv[10], p,  "1960"); GLD(pv[11], p,  "2156");
    GLD(pv[12], p,  "2352"); GLD(pv[13], p,  "2548"); GLD(pv[14], p,  "2744");
    GLD(pv[15], p,  "2940"); GLD(pv[16], p,  "3136"); GLD(pv[17], p,  "3332");
    GLD(pv[18], p,  "3528"); GLD(pv[19], p,  "3724"); GLD(pv[20], p,  "3920");
    GLD(pv[21], p2, "0");    GLD(pv[22], p2, "196");  GLD(pv[23], p2, "392");
    GLD(pv[24], p2, "588");  GLD(pv[25], p2, "784");  GLD(pv[26], p2, "980");
    GLD(pv[27], p2, "1176"); GLD(pv[28], p2, "1372"); GLD(pv[29], p2, "1568");

    asm volatile("s_waitcnt vmcnt(0)" ::: "memory");
    __builtin_amdgcn_sched_barrier(0);   // consumers must not hoist above the wait

    // ---- GIoU(gt box, pred box k) for k=0 (ch 0..3) and k=1 (ch 5..8) ----
    const float gx1 = gv[0], gy1 = gv[1];
    const float gx2 = gv[0] + gv[2], gy2 = gv[1] + gv[3];
    const float ga  = (gx2 - gx1) * (gy2 - gy1);

    float l[2];
    #pragma unroll
    for (int k = 0; k < 2; ++k) {
        const int o = k * 5;
        float px1 = pv[o + 0], py1 = pv[o + 1];
        float px2 = px1 + pv[o + 2], py2 = py1 + pv[o + 3];
        float ix1 = fmaxf(gx1, px1), iy1 = fmaxf(gy1, py1);
        float ix2 = fminf(gx2, px2), iy2 = fminf(gy2, py2);
        float inter = fmaxf(ix2 - ix1, 0.0f) * fmaxf(iy2 - iy1, 0.0f);
        float pa  = (px2 - px1) * (py2 - py1);
        float uni = ga + pa - inter;
        float iou = inter / (uni + GEPS);
        float cx1 = fminf(gx1, px1), cy1 = fminf(gy1, py1);
        float cx2 = fmaxf(gx2, px2), cy2 = fmaxf(gy2, py2);
        float enc = (cx2 - cx1) * (cy2 - cy1);
        l[k] = 1.0f - (iou - (enc - uni) / (enc + GEPS));
    }

    // jnp.argmax first-max tie-break: arg = 1 iff l2 > l1
    float r0, r1;
    if (l[1] > l[0]) { r0 = 0.0f;   r1 = gv[9]; }
    else             { r0 = gv[4];  r1 = 0.0f;  }
    const float appears = fmaxf(r0, r1);

    float s = 0.0f;
    float d;
    d = gv[0] - pv[0]; s += d * d * r0 * LAMB_COORD;
    d = gv[1] - pv[1]; s += d * d * r0 * LAMB_COORD;
    d = gv[5] - pv[5]; s += d * d * r1 * LAMB_COORD;
    d = gv[6] - pv[6]; s += d * d * r1 * LAMB_COORD;
    d = sqrtf(gv[2]) - sqrtf(pv[2]); s += d * d * r0 * LAMB_COORD;
    d = sqrtf(gv[3]) - sqrtf(pv[3]); s += d * d * r0 * LAMB_COORD;
    d = sqrtf(gv[7]) - sqrtf(pv[7]); s += d * d * r1 * LAMB_COORD;
    d = sqrtf(gv[8]) - sqrtf(pv[8]); s += d * d * r1 * LAMB_COORD;
    d = gv[4] - pv[4]; { float d2 = d * d; s += d2 * r0 + d2 * (1.0f - r0) * LAMB_NOOBJ; }
    d = gv[9] - pv[9]; { float d2 = d * d; s += d2 * r1 + d2 * (1.0f - r1) * LAMB_NOOBJ; }

    float cls = 0.0f;
    #pragma unroll
    for (int c = 10; c < 30; ++c) {
        float dc = gv[c] - pv[c];
        cls += dc * dc;
    }
    s += cls * appears;

    // ---- Reduce: 64-lane wave shuffle -> LDS -> one atomic per block ----
    #pragma unroll
    for (int off = 32; off > 0; off >>= 1)
        s += __shfl_down(s, off, 64);

    __shared__ float wsum[4];
    const int lane = threadIdx.x & 63;
    const int wid  = threadIdx.x >> 6;
    if (lane == 0) wsum[wid] = s;
    __syncthreads();
    if (threadIdx.x == 0) {
        atomicAdd(out, wsum[0] + wsum[1] + wsum[2] + wsum[3]);
    }
}

extern "C" void kernel_launch(void* const* d_in, const int* in_sizes, int n_in,
                              void* d_out, int out_size, void* d_ws, size_t ws_size,
                              hipStream_t stream) {
    const float* gt   = (const float*)d_in[0];
    const float* pred = (const float*)d_in[1];
    float* out = (float*)d_out;

    const int B = in_sizes[0] / 1470;    // 16384
    const int ncells = B * 49;           // 802816 = 3136 * 256
    const int grid = ncells / 256;       // 3136

    hipMemsetAsync(out, 0, sizeof(float) * out_size, stream);
    yolo_loss_kernel<<<grid, 256, 0, stream>>>(gt, pred, out);
}